// Round 1
// baseline (596.708 us; speedup 1.0000x reference)
//
#include <hip/hip_runtime.h>
#include <math.h>

#define SEQ 2048
#define DM  1024
#define DI  64
#define NB  8

// ---------------------------------------------------------------------------
// Kernel A: fused QKV projection.  grid (64, 3), block 256.
// blockIdx.y selects matrix: 0->Q, 1->K, 2->V (uniform -> scalar W loads).
// Thread t owns one row (256 rows/block); W row elements are block-uniform
// so they land in SGPRs -> inner loop is pure v_fmac_f32.
// ---------------------------------------------------------------------------
__global__ __launch_bounds__(256)
void proj_kernel(const float* __restrict__ X,
                 const float* __restrict__ Wq, const float* __restrict__ bq,
                 const float* __restrict__ Wk, const float* __restrict__ bk,
                 const float* __restrict__ Wv, const float* __restrict__ bv,
                 float* __restrict__ Qo, float* __restrict__ Ko, float* __restrict__ Vo)
{
    __shared__ float Xs[256][33];   // 32-wide k-chunk, pad 33 -> 2-way (free)
    const int t   = threadIdx.x;
    const int mat = blockIdx.y;
    const float* W; const float* bias; float* Out;
    if (mat == 0)      { W = Wq; bias = bq; Out = Qo; }
    else if (mat == 1) { W = Wk; bias = bk; Out = Ko; }
    else               { W = Wv; bias = bv; Out = Vo; }
    const int r0 = blockIdx.x * 256;

    float acc[DI];
#pragma unroll
    for (int c = 0; c < DI; ++c) acc[c] = 0.f;

    for (int k0 = 0; k0 < DM; k0 += 32) {
        __syncthreads();
        // stage X[256 rows][32 k] coalesced (1 KiB contiguous per instr)
#pragma unroll
        for (int i = 0; i < 8; ++i) {
            const int lin = i * 1024 + t * 4;
            const int rr = lin >> 5, kk = lin & 31;
            const float4 x4 = *(const float4*)(X + (size_t)(r0 + rr) * DM + (k0 + kk));
            Xs[rr][kk + 0] = x4.x; Xs[rr][kk + 1] = x4.y;
            Xs[rr][kk + 2] = x4.z; Xs[rr][kk + 3] = x4.w;
        }
        __syncthreads();
        const float* Wbase = W + (size_t)k0 * DI;
#pragma unroll 2
        for (int kk = 0; kk < 32; ++kk) {
            const float xv = Xs[t][kk];
            const float* wrow = Wbase + kk * DI;   // uniform -> s_load
#pragma unroll
            for (int c = 0; c < DI; ++c)
                acc[c] = fmaf(xv, wrow[c], acc[c]);
        }
    }
    float* orow = Out + (size_t)(r0 + t) * DI;
#pragma unroll
    for (int c = 0; c < DI; c += 4) {
        float4 o4 = { acc[c] + bias[c], acc[c+1] + bias[c+1],
                      acc[c+2] + bias[c+2], acc[c+3] + bias[c+3] };
        *(float4*)(orow + c) = o4;
    }
}

// ---------------------------------------------------------------------------
// Kernel B: flash attention (online softmax) + fused output projection.
// grid 256 = 8 batches x 32 q-tiles of 64 rows.  block 256 threads.
// thread (tr = t>>4, tc = t&15) owns a 4x4 micro-tile: rows 4tr.., cols 4tc..
// LDS layouts are d-major (transposed) so hot loops use ds_read_b128.
// Per-row softmax state reduced across the 16 lanes of a tr-group (shfl_xor).
// P round-trips through LDS in MFMA-friendly transposed form; all P/ctx LDS
// traffic is same-wave (tr-group <-> wave), so no extra barriers needed.
// ---------------------------------------------------------------------------
__global__ __launch_bounds__(256)
void attn_kernel(const float* __restrict__ Qg, const float* __restrict__ Kg,
                 const float* __restrict__ Vg, const float* __restrict__ W0,
                 const float* __restrict__ b0, float* __restrict__ Out)
{
    __shared__ float Qt[64][68];   // Qt[d][r]
    __shared__ float Kt[64][68];   // Kt[d][j]
    __shared__ float Vs[64][68];   // Vs[j][c]
    __shared__ float Pt[64][68];   // Pt[j][r], reused for ctx[c][r] at the end
    __shared__ float W0s[64][68];  // W0s[c][o]

    const int t  = threadIdx.x;
    const int tr = t >> 4;         // 0..15
    const int tc = t & 15;         // 0..15
    const int b  = blockIdx.x >> 5;
    const int qb = blockIdx.x & 31;
    const int q0 = qb * 64;

    const float* Qb = Qg + ((size_t)b * SEQ + q0) * DI;
    const float* Kb = Kg + (size_t)b * SEQ * DI;
    const float* Vb = Vg + (size_t)b * SEQ * DI;

    // stage Q transposed
#pragma unroll
    for (int p = 0; p < 4; ++p) {
        const int j  = tr + p * 16;
        const int d0 = tc * 4;
        const float4 q4 = *(const float4*)(Qb + (size_t)j * DI + d0);
        Qt[d0+0][j] = q4.x; Qt[d0+1][j] = q4.y; Qt[d0+2][j] = q4.z; Qt[d0+3][j] = q4.w;
    }
    // stage W0 natural
#pragma unroll
    for (int i = 0; i < 4; ++i) {
        const int e = i * 1024 + t * 4;
        *(float4*)(&W0s[e >> 6][e & 63]) = *(const float4*)(W0 + e);
    }

    float m_[4], l_[4], acc[4][4];
#pragma unroll
    for (int i = 0; i < 4; ++i) {
        m_[i] = -INFINITY; l_[i] = 0.f;
#pragma unroll
        for (int j = 0; j < 4; ++j) acc[i][j] = 0.f;
    }

    const float scale = 0.125f;    // 1/sqrt(64)

    for (int kt = 0; kt <= qb; ++kt) {
        const int k0 = kt * 64;
        __syncthreads();
        // stage K transposed
#pragma unroll
        for (int p = 0; p < 4; ++p) {
            const int j  = tr + p * 16;
            const int d0 = tc * 4;
            const float4 k4 = *(const float4*)(Kb + (size_t)(k0 + j) * DI + d0);
            Kt[d0+0][j] = k4.x; Kt[d0+1][j] = k4.y; Kt[d0+2][j] = k4.z; Kt[d0+3][j] = k4.w;
        }
        // stage V natural
#pragma unroll
        for (int i = 0; i < 4; ++i) {
            const int e = i * 1024 + t * 4;
            *(float4*)(&Vs[e >> 6][e & 63]) = *(const float4*)(Vb + (size_t)k0 * DI + e);
        }
        __syncthreads();

        // S = Q K^T (4x4 per thread), d-major b128 reads
        float s[4][4];
#pragma unroll
        for (int i = 0; i < 4; ++i)
#pragma unroll
            for (int j = 0; j < 4; ++j) s[i][j] = 0.f;

        for (int d = 0; d < 64; ++d) {
            const float4 q4 = *(const float4*)(&Qt[d][tr * 4]);
            const float4 k4 = *(const float4*)(&Kt[d][tc * 4]);
            const float qa[4] = {q4.x, q4.y, q4.z, q4.w};
            const float ka[4] = {k4.x, k4.y, k4.z, k4.w};
#pragma unroll
            for (int i = 0; i < 4; ++i)
#pragma unroll
                for (int j = 0; j < 4; ++j)
                    s[i][j] = fmaf(qa[i], ka[j], s[i][j]);
        }

        // scale + causal mask (diagonal tile only)
        if (kt == qb) {
#pragma unroll
            for (int i = 0; i < 4; ++i)
#pragma unroll
                for (int j = 0; j < 4; ++j)
                    s[i][j] = (tc * 4 + j <= tr * 4 + i) ? s[i][j] * scale : -INFINITY;
        } else {
#pragma unroll
            for (int i = 0; i < 4; ++i)
#pragma unroll
                for (int j = 0; j < 4; ++j) s[i][j] *= scale;
        }

        // online softmax per row (reduce across the 16 lanes of the tr-group)
#pragma unroll
        for (int i = 0; i < 4; ++i) {
            float mt = fmaxf(fmaxf(s[i][0], s[i][1]), fmaxf(s[i][2], s[i][3]));
            mt = fmaxf(mt, __shfl_xor(mt, 1));
            mt = fmaxf(mt, __shfl_xor(mt, 2));
            mt = fmaxf(mt, __shfl_xor(mt, 4));
            mt = fmaxf(mt, __shfl_xor(mt, 8));
            const float mn = fmaxf(m_[i], mt);
            const float al = __expf(m_[i] - mn);   // first tile: exp(-inf)=0
            float rs = 0.f;
#pragma unroll
            for (int j = 0; j < 4; ++j) { s[i][j] = __expf(s[i][j] - mn); rs += s[i][j]; }
            rs += __shfl_xor(rs, 1);
            rs += __shfl_xor(rs, 2);
            rs += __shfl_xor(rs, 4);
            rs += __shfl_xor(rs, 8);
            l_[i] = l_[i] * al + rs;
            m_[i] = mn;
#pragma unroll
            for (int j = 0; j < 4; ++j) acc[i][j] *= al;
        }

        // write P transposed (same-wave producer/consumer: no barrier needed)
#pragma unroll
        for (int j = 0; j < 4; ++j) {
            const float4 p4 = { s[0][j], s[1][j], s[2][j], s[3][j] };
            *(float4*)(&Pt[tc * 4 + j][tr * 4]) = p4;
        }

        // acc += P V
        for (int jj = 0; jj < 64; ++jj) {
            const float4 p4 = *(const float4*)(&Pt[jj][tr * 4]);
            const float4 v4 = *(const float4*)(&Vs[jj][tc * 4]);
            const float pa[4] = {p4.x, p4.y, p4.z, p4.w};
            const float va[4] = {v4.x, v4.y, v4.z, v4.w};
#pragma unroll
            for (int i = 0; i < 4; ++i)
#pragma unroll
                for (int j = 0; j < 4; ++j)
                    acc[i][j] = fmaf(pa[i], va[j], acc[i][j]);
        }
    }

    // normalize
#pragma unroll
    for (int i = 0; i < 4; ++i) {
        const float inv = 1.0f / l_[i];
#pragma unroll
        for (int j = 0; j < 4; ++j) acc[i][j] *= inv;
    }

    // stage ctx transposed into Pt (same-wave), then out = ctx @ W0 + b0
    __syncthreads();
#pragma unroll
    for (int j = 0; j < 4; ++j) {
        const float4 c4 = { acc[0][j], acc[1][j], acc[2][j], acc[3][j] };
        *(float4*)(&Pt[tc * 4 + j][tr * 4]) = c4;
    }

    float o_[4][4];
#pragma unroll
    for (int i = 0; i < 4; ++i)
#pragma unroll
        for (int j = 0; j < 4; ++j) o_[i][j] = 0.f;

    for (int c = 0; c < 64; ++c) {
        const float4 c4 = *(const float4*)(&Pt[c][tr * 4]);
        const float4 w4 = *(const float4*)(&W0s[c][tc * 4]);
        const float ca[4] = {c4.x, c4.y, c4.z, c4.w};
        const float wa[4] = {w4.x, w4.y, w4.z, w4.w};
#pragma unroll
        for (int i = 0; i < 4; ++i)
#pragma unroll
            for (int j = 0; j < 4; ++j)
                o_[i][j] = fmaf(ca[i], wa[j], o_[i][j]);
    }

#pragma unroll
    for (int i = 0; i < 4; ++i) {
        const int row = q0 + tr * 4 + i;
        float4 r4 = { o_[i][0] + b0[tc*4+0], o_[i][1] + b0[tc*4+1],
                      o_[i][2] + b0[tc*4+2], o_[i][3] + b0[tc*4+3] };
        *(float4*)(Out + ((size_t)b * SEQ + row) * DI + tc * 4) = r4;
    }
}

// ---------------------------------------------------------------------------
extern "C" void kernel_launch(void* const* d_in, const int* in_sizes, int n_in,
                              void* d_out, int out_size, void* d_ws, size_t ws_size,
                              hipStream_t stream) {
    const float* X  = (const float*)d_in[0];
    const float* Wk = (const float*)d_in[1];
    const float* bk = (const float*)d_in[2];
    const float* Wq = (const float*)d_in[3];
    const float* bq = (const float*)d_in[4];
    const float* Wv = (const float*)d_in[5];
    const float* bv = (const float*)d_in[6];
    const float* W0 = (const float*)d_in[7];
    const float* b0 = (const float*)d_in[8];
    float* Out = (float*)d_out;

    const size_t qkv_elems = (size_t)NB * SEQ * DI;   // 1,048,576 floats each
    float* Qw = (float*)d_ws;
    float* Kw = Qw + qkv_elems;
    float* Vw = Kw + qkv_elems;

    proj_kernel<<<dim3(64, 3), 256, 0, stream>>>(X, Wq, bq, Wk, bk, Wv, bv, Qw, Kw, Vw);
    attn_kernel<<<dim3(256), 256, 0, stream>>>(Qw, Kw, Vw, W0, b0, Out);
}

// Round 2
// 207.410 us; speedup vs baseline: 2.8770x; 2.8770x over previous
//
#include <hip/hip_runtime.h>
#include <math.h>

#define SEQ 2048
#define DM  1024
#define DI  64
#define NB  8

typedef __attribute__((ext_vector_type(8))) short short8;
typedef __attribute__((ext_vector_type(4))) float f32x4;
typedef __attribute__((ext_vector_type(4))) unsigned short ush4;

#define MFMA16(a,b,c) __builtin_amdgcn_mfma_f32_16x16x32_bf16(a, b, c, 0, 0, 0)

// round-to-nearest-even fp32 -> bf16
__device__ __forceinline__ unsigned short f2bf(float f) {
    unsigned int u = __builtin_bit_cast(unsigned int, f);
    u += 0x7fffu + ((u >> 16) & 1u);
    return (unsigned short)(u >> 16);
}

// ---------------------------------------------------------------------------
// Kernel 0: weight prep. blocks 0..47: Wcat^T bf16 [192][1024] (rows 0-63 =
// Wq^T * 0.125 (exact pow2 fold of 1/sqrt(64)), 64-127 = Wk^T, 128-191 = Wv^T).
// block 48: W0^T bf16 [64][64].
// ---------------------------------------------------------------------------
__global__ __launch_bounds__(256)
void convert_kernel(const float* __restrict__ Wq, const float* __restrict__ Wk,
                    const float* __restrict__ Wv, const float* __restrict__ W0,
                    unsigned short* __restrict__ Wt, unsigned short* __restrict__ W0t)
{
    __shared__ float tile[64][65];
    const int t = threadIdx.x;
    const int blk = blockIdx.x;
    const float* src; unsigned short* dst; int k0; float scale; int rstride;
    if (blk < 48) {
        const int mm = blk >> 4, kt = blk & 15;
        src = (mm == 0) ? Wq : (mm == 1) ? Wk : Wv;
        dst = Wt + (size_t)mm * 64 * 1024;
        k0 = kt * 64; scale = (mm == 0) ? 0.125f : 1.0f; rstride = 1024;
    } else {
        src = W0; dst = W0t; k0 = 0; scale = 1.0f; rstride = 64;
    }
#pragma unroll
    for (int i = 0; i < 4; ++i) {
        const int e = i * 1024 + t * 4;
        const int kk = e >> 6, o = e & 63;
        const float4 v = *(const float4*)(src + (size_t)(k0 + kk) * 64 + o);
        tile[kk][o] = v.x; tile[kk][o + 1] = v.y; tile[kk][o + 2] = v.z; tile[kk][o + 3] = v.w;
    }
    __syncthreads();
#pragma unroll
    for (int h = 0; h < 2; ++h) {
        const int o = (t >> 3) + 32 * h;
        const int kp = (t & 7) * 8;
        union { short8 v; unsigned short u[8]; } pk;
#pragma unroll
        for (int j = 0; j < 8; ++j) pk.u[j] = f2bf(tile[kp + j][o] * scale);
        *(short8*)(dst + (size_t)o * rstride + k0 + kp) = pk.v;
    }
}

// ---------------------------------------------------------------------------
// Kernel 1: fused QKV projection via bf16 MFMA.  grid 256 (64-token tiles),
// block 256 = 4 waves; wave w owns tokens 16w..16w+15, 12 n-tiles (Q|K|V).
// X converted fp32->bf16 while staging; W^T pre-converted (kernel 0).
// Outputs: Q,K row-major bf16; V stored TRANSPOSED ([b][dv][t]) via LDS so
// attention's PV B-fragments are contiguous b128 loads.
// LDS pads: row stride 40 bf16 = 80 B (16B-aligned, conflict-light).
// ---------------------------------------------------------------------------
__global__ __launch_bounds__(256)
void proj_kernel(const float* __restrict__ X, const unsigned short* __restrict__ Wt,
                 const float* __restrict__ bq, const float* __restrict__ bk,
                 const float* __restrict__ bv,
                 unsigned short* __restrict__ Qg, unsigned short* __restrict__ Kg,
                 unsigned short* __restrict__ Vtg)
{
    __shared__ alignas(16) unsigned short Xs[64][40];
    __shared__ alignas(16) unsigned short Ws[192][40];
    const int t = threadIdx.x;
    const int lane = t & 63, w = t >> 6;
    const int quad = lane >> 4, n = lane & 15;
    const int r0 = blockIdx.x * 64;

    const f32x4 ZERO = {0.f, 0.f, 0.f, 0.f};
    f32x4 acc[12];
#pragma unroll
    for (int i = 0; i < 12; ++i) acc[i] = ZERO;

    const int xrow = t >> 2, xkp = (t & 3) * 8;
    const float* xp = X + (size_t)(r0 + xrow) * DM + xkp;

    for (int k0 = 0; k0 < DM; k0 += 32) {
        const float4 a4 = *(const float4*)(xp + k0);
        const float4 b4 = *(const float4*)(xp + k0 + 4);
        short8 wseg[3];
#pragma unroll
        for (int i = 0; i < 3; ++i) {
            const int seg = i * 256 + t;                 // 0..767 = 192 rows x 4 parts
            wseg[i] = *(const short8*)(Wt + (size_t)(seg >> 2) * DM + k0 + (seg & 3) * 8);
        }
        __syncthreads();                                  // prev-iter LDS reads done
        union { short8 v; unsigned short u[8]; } px;
        px.u[0] = f2bf(a4.x); px.u[1] = f2bf(a4.y); px.u[2] = f2bf(a4.z); px.u[3] = f2bf(a4.w);
        px.u[4] = f2bf(b4.x); px.u[5] = f2bf(b4.y); px.u[6] = f2bf(b4.z); px.u[7] = f2bf(b4.w);
        *(short8*)&Xs[xrow][xkp] = px.v;
#pragma unroll
        for (int i = 0; i < 3; ++i) {
            const int seg = i * 256 + t;
            *(short8*)&Ws[seg >> 2][(seg & 3) * 8] = wseg[i];
        }
        __syncthreads();
        const short8 af = *(const short8*)&Xs[16 * w + n][quad * 8];
#pragma unroll
        for (int nt = 0; nt < 12; ++nt) {
            const short8 bf = *(const short8*)&Ws[nt * 16 + n][quad * 8];
            acc[nt] = MFMA16(af, bf, acc[nt]);
        }
    }
    // epilogue.  D layout: col = lane&15 = o, row = quad*4+reg = token (in 16-slice)
    const int tokbase = r0 + 16 * w + quad * 4;
#pragma unroll
    for (int nt = 0; nt < 4; ++nt) {
        const int o = 16 * nt + n;
        const float bqv = bq[o] * 0.125f;
        const float bkv = bk[o];
#pragma unroll
        for (int r = 0; r < 4; ++r) {
            Qg[(size_t)(tokbase + r) * DI + o] = f2bf(acc[nt][r] + bqv);
            Kg[(size_t)(tokbase + r) * DI + o] = f2bf(acc[nt + 4][r] + bkv);
        }
    }
    __syncthreads();                                      // all waves done with Ws
    unsigned short (*Vtile)[72] = (unsigned short (*)[72])&Ws[0][0];
#pragma unroll
    for (int nt = 0; nt < 4; ++nt) {
        const int o = 16 * nt + n;
        const float bvv = bv[o];
#pragma unroll
        for (int r = 0; r < 4; ++r)
            Vtile[16 * w + quad * 4 + r][o] = f2bf(acc[nt + 8][r] + bvv);
    }
    __syncthreads();
    // V^T store: lane -> dv, wave w -> its own 16 tokens (32 B contiguous)
    union { short8 v; unsigned short u[8]; } v0, v1;
#pragma unroll
    for (int i = 0; i < 8; ++i) {
        v0.u[i] = Vtile[16 * w + i][lane];
        v1.u[i] = Vtile[16 * w + 8 + i][lane];
    }
    const int bidx = r0 >> 11;
    const int tloc = (r0 & 2047) + 16 * w;
    unsigned short* vp = Vtg + (size_t)bidx * DI * SEQ + (size_t)lane * SEQ + tloc;
    *(short8*)vp = v0.v;
    *(short8*)(vp + 8) = v1.v;
}

// ---------------------------------------------------------------------------
// Kernel 2: flash attention + fused W0 projection.  1024 one-wave blocks
// (no __syncthreads anywhere): qt = 127-(idx>>3) (heavy-first), b = idx&7
// (= XCD id -> per-XCD K/V L2 locality).  Computes S^T = K·Q^T so the C/D
// column index (lane&15) is the q-row: softmax stats are per-lane, reduced
// across quads with two shfl_xor.  P -> LDS (wave-local) -> A-fragment for PV.
// ---------------------------------------------------------------------------
__global__ __launch_bounds__(64)
void attn_kernel(const unsigned short* __restrict__ Qg, const unsigned short* __restrict__ Kg,
                 const unsigned short* __restrict__ Vtg, const unsigned short* __restrict__ W0t,
                 const float* __restrict__ b0, float* __restrict__ Out)
{
    __shared__ alignas(16) unsigned short P[16][72];      // 72: keep rows 16B-aligned
    const int lane = threadIdx.x;
    const int quad = lane >> 4, n = lane & 15;
    const int idx = blockIdx.x;
    const int qt = 127 - (idx >> 3);
    const int b = idx & 7;
    const int q0 = qt * 16;

    const unsigned short* Qb = Qg + ((size_t)b * SEQ + q0) * DI;
    const unsigned short* Kb = Kg + (size_t)b * SEQ * DI;
    const unsigned short* Vb = Vtg + (size_t)b * DI * SEQ;

    const short8 qf0 = *(const short8*)(Qb + n * DI + quad * 8);
    const short8 qf1 = *(const short8*)(Qb + n * DI + 32 + quad * 8);

    const f32x4 ZERO = {0.f, 0.f, 0.f, 0.f};
    float m = -INFINITY, l = 0.f;
    f32x4 ctx[4];
#pragma unroll
    for (int i = 0; i < 4; ++i) ctx[i] = ZERO;

    const int C = (qt >> 2) + 1;                          // causal 64-key chunks
    for (int kt = 0; kt < C; ++kt) {
        const int k0 = kt * 64;
        f32x4 sv[4];
#pragma unroll
        for (int tt = 0; tt < 4; ++tt) {                  // S^T tile: rows = keys
            const unsigned short* kr = Kb + (size_t)(k0 + 16 * tt + n) * DI + quad * 8;
            const short8 kf0 = *(const short8*)kr;
            const short8 kf1 = *(const short8*)(kr + 32);
            f32x4 a = ZERO;
            a = MFMA16(kf0, qf0, a);
            a = MFMA16(kf1, qf1, a);
            sv[tt] = a;                                   // S^T[key=k0+16t+quad*4+r][q=q0+n]
        }
        if (kt == C - 1) {                                // only last chunk straddles diag
#pragma unroll
            for (int tt = 0; tt < 4; ++tt)
#pragma unroll
                for (int r = 0; r < 4; ++r)
                    if (k0 + 16 * tt + quad * 4 + r > q0 + n) sv[tt][r] = -INFINITY;
        }
        float rmax = sv[0][0];
#pragma unroll
        for (int tt = 0; tt < 4; ++tt)
#pragma unroll
            for (int r = 0; r < 4; ++r) rmax = fmaxf(rmax, sv[tt][r]);
        rmax = fmaxf(rmax, __shfl_xor(rmax, 16));
        rmax = fmaxf(rmax, __shfl_xor(rmax, 32));
        const float mnew = fmaxf(m, rmax);
        const float alpha = __expf(m - mnew);             // first chunk: exp(-inf)=0
        float rsum = 0.f;
#pragma unroll
        for (int tt = 0; tt < 4; ++tt) {
            union { ush4 v; unsigned short u[4]; } pw;
#pragma unroll
            for (int r = 0; r < 4; ++r) {
                const float p = __expf(sv[tt][r] - mnew);
                rsum += p;
                pw.u[r] = f2bf(p);
            }
            *(ush4*)&P[n][16 * tt + quad * 4] = pw.v;     // P[q][key] for A-frag reads
        }
        rsum += __shfl_xor(rsum, 16);
        rsum += __shfl_xor(rsum, 32);
        l = l * alpha + rsum;
        m = mnew;
        float aL[4];
#pragma unroll
        for (int r = 0; r < 4; ++r) aL[r] = __shfl(alpha, quad * 4 + r);
#pragma unroll
        for (int nt = 0; nt < 4; ++nt)
#pragma unroll
            for (int r = 0; r < 4; ++r) ctx[nt][r] *= aL[r];
#pragma unroll
        for (int s = 0; s < 2; ++s) {                     // ctx += P V  (K-dim = 64 keys)
            const short8 pf = *(const short8*)&P[n][s * 32 + quad * 8];
#pragma unroll
            for (int nt = 0; nt < 4; ++nt) {
                const short8 vf = *(const short8*)(Vb + (size_t)(n + 16 * nt) * SEQ + k0 + s * 32 + quad * 8);
                ctx[nt] = MFMA16(pf, vf, ctx[nt]);
            }
        }
    }
    // normalize; ctx rows are q = quad*4+r -> fetch l from lane quad*4+r
    float invl[4];
#pragma unroll
    for (int r = 0; r < 4; ++r) invl[r] = 1.f / __shfl(l, quad * 4 + r);
#pragma unroll
    for (int nt = 0; nt < 4; ++nt)
#pragma unroll
        for (int r = 0; r < 4; ++r)
            P[quad * 4 + r][n + 16 * nt] = f2bf(ctx[nt][r] * invl[r]);   // ctx[q][dv]
    // out = ctx @ W0 + b0
    f32x4 oacc[4];
#pragma unroll
    for (int i = 0; i < 4; ++i) oacc[i] = ZERO;
#pragma unroll
    for (int s = 0; s < 2; ++s) {
        const short8 cf = *(const short8*)&P[n][s * 32 + quad * 8];
#pragma unroll
        for (int nt = 0; nt < 4; ++nt) {
            const short8 wf = *(const short8*)(W0t + (size_t)(n + 16 * nt) * DI + s * 32 + quad * 8);
            oacc[nt] = MFMA16(cf, wf, oacc[nt]);
        }
    }
#pragma unroll
    for (int nt = 0; nt < 4; ++nt) {
        const float bb = b0[n + 16 * nt];
#pragma unroll
        for (int r = 0; r < 4; ++r)
            Out[((size_t)b * SEQ + q0 + quad * 4 + r) * DI + n + 16 * nt] = oacc[nt][r] + bb;
    }
}

// ---------------------------------------------------------------------------
extern "C" void kernel_launch(void* const* d_in, const int* in_sizes, int n_in,
                              void* d_out, int out_size, void* d_ws, size_t ws_size,
                              hipStream_t stream) {
    const float* X  = (const float*)d_in[0];
    const float* Wk = (const float*)d_in[1];
    const float* bk = (const float*)d_in[2];
    const float* Wq = (const float*)d_in[3];
    const float* bq = (const float*)d_in[4];
    const float* Wv = (const float*)d_in[5];
    const float* bv = (const float*)d_in[6];
    const float* W0 = (const float*)d_in[7];
    const float* b0 = (const float*)d_in[8];
    float* Out = (float*)d_out;

    unsigned char* ws = (unsigned char*)d_ws;
    unsigned short* Wt  = (unsigned short*)ws;                        // 192*1024*2 = 384 KiB
    unsigned short* W0t = (unsigned short*)(ws + 393216);             // 64*64*2 = 8 KiB
    unsigned short* Qw  = (unsigned short*)(ws + 401408);             // 16384*64*2 = 2 MiB
    unsigned short* Kw  = (unsigned short*)(ws + 401408 + 2097152);   // 2 MiB
    unsigned short* Vt  = (unsigned short*)(ws + 401408 + 4194304);   // 2 MiB ([8][64][2048])

    convert_kernel<<<49, 256, 0, stream>>>(Wq, Wk, Wv, W0, Wt, W0t);
    proj_kernel<<<256, 256, 0, stream>>>(X, Wt, bq, bk, bv, Qw, Kw, Vt);
    attn_kernel<<<1024, 64, 0, stream>>>(Qw, Kw, Vt, W0t, b0, Out);
}

// Round 3
// 191.821 us; speedup vs baseline: 3.1108x; 1.0813x over previous
//
#include <hip/hip_runtime.h>
#include <math.h>

#define SEQ 2048
#define DM  1024
#define DI  64
#define NB  8

typedef __attribute__((ext_vector_type(8))) short short8;
typedef __attribute__((ext_vector_type(4))) float f32x4;
typedef __attribute__((ext_vector_type(4))) unsigned short ush4;

#define MFMA16(a,b,c) __builtin_amdgcn_mfma_f32_16x16x32_bf16(a, b, c, 0, 0, 0)

// round-to-nearest-even fp32 -> bf16
__device__ __forceinline__ unsigned short f2bf(float f) {
    unsigned int u = __builtin_bit_cast(unsigned int, f);
    u += 0x7fffu + ((u >> 16) & 1u);
    return (unsigned short)(u >> 16);
}

// ---------------------------------------------------------------------------
// Kernel 0: weight prep. blocks 0..47: Wcat^T bf16 [192][1024] (rows 0-63 =
// Wq^T * 0.125 (exact pow2 fold of 1/sqrt(64)), 64-127 = Wk^T, 128-191 = Wv^T).
// block 48: W0^T bf16 [64][64].
// ---------------------------------------------------------------------------
__global__ __launch_bounds__(256)
void convert_kernel(const float* __restrict__ Wq, const float* __restrict__ Wk,
                    const float* __restrict__ Wv, const float* __restrict__ W0,
                    unsigned short* __restrict__ Wt, unsigned short* __restrict__ W0t)
{
    __shared__ float tile[64][65];
    const int t = threadIdx.x;
    const int blk = blockIdx.x;
    const float* src; unsigned short* dst; int k0; float scale; int rstride;
    if (blk < 48) {
        const int mm = blk >> 4, kt = blk & 15;
        src = (mm == 0) ? Wq : (mm == 1) ? Wk : Wv;
        dst = Wt + (size_t)mm * 64 * 1024;
        k0 = kt * 64; scale = (mm == 0) ? 0.125f : 1.0f; rstride = 1024;
    } else {
        src = W0; dst = W0t; k0 = 0; scale = 1.0f; rstride = 64;
    }
#pragma unroll
    for (int i = 0; i < 4; ++i) {
        const int e = i * 1024 + t * 4;
        const int kk = e >> 6, o = e & 63;
        const float4 v = *(const float4*)(src + (size_t)(k0 + kk) * 64 + o);
        tile[kk][o] = v.x; tile[kk][o + 1] = v.y; tile[kk][o + 2] = v.z; tile[kk][o + 3] = v.w;
    }
    __syncthreads();
#pragma unroll
    for (int h = 0; h < 2; ++h) {
        const int o = (t >> 3) + 32 * h;
        const int kp = (t & 7) * 8;
        union { short8 v; unsigned short u[8]; } pk;
#pragma unroll
        for (int j = 0; j < 8; ++j) pk.u[j] = f2bf(tile[kp + j][o] * scale);
        *(short8*)(dst + (size_t)o * rstride + k0 + kp) = pk.v;
    }
}

// ---------------------------------------------------------------------------
// Kernel 1: QKV projection, barrier-free main loop.  grid 1024 (16-token
// tiles), block 256 = 4 waves; ALL waves share the block's 16 tokens and
// split K 4 ways (wave w: k in [256w, 256w+256)).  A- and B-fragments load
// DIRECTLY from global (X: fp32->bf16 in-register; W^T: bf16, L2-resident).
// One __syncthreads, then an LDS merge of the 4 partial sums + vectorized
// bf16 stores (Q,K row-major; V transposed [b][dv][t]).
// ---------------------------------------------------------------------------
__global__ __launch_bounds__(256)
void proj_kernel(const float* __restrict__ X, const unsigned short* __restrict__ Wt,
                 const float* __restrict__ bq, const float* __restrict__ bk,
                 const float* __restrict__ bv,
                 unsigned short* __restrict__ Qg, unsigned short* __restrict__ Kg,
                 unsigned short* __restrict__ Vtg)
{
    __shared__ float Facc[4][16][200];     // [wave][token][out 0..191], stride 200 (800B, 16B-mult)
    const int t = threadIdx.x;
    const int lane = t & 63, w = t >> 6;
    const int quad = lane >> 4, n = lane & 15;
    const int r0 = blockIdx.x * 16;

    const f32x4 ZERO = {0.f, 0.f, 0.f, 0.f};
    f32x4 acc[12];
#pragma unroll
    for (int i = 0; i < 12; ++i) acc[i] = ZERO;

    const float* xp = X + (size_t)(r0 + n) * DM + w * 256 + quad * 8;
    const unsigned short* wp = Wt + (size_t)n * DM + w * 256 + quad * 8;

    for (int k0 = 0; k0 < 256; k0 += 32) {
        const float4 a4 = *(const float4*)(xp + k0);
        const float4 b4 = *(const float4*)(xp + k0 + 4);
        union { short8 v; unsigned short u[8]; } px;
        px.u[0] = f2bf(a4.x); px.u[1] = f2bf(a4.y); px.u[2] = f2bf(a4.z); px.u[3] = f2bf(a4.w);
        px.u[4] = f2bf(b4.x); px.u[5] = f2bf(b4.y); px.u[6] = f2bf(b4.z); px.u[7] = f2bf(b4.w);
#pragma unroll
        for (int nt = 0; nt < 12; ++nt) {
            const short8 bf = *(const short8*)(wp + (size_t)nt * 16 * DM + k0);
            acc[nt] = MFMA16(px.v, bf, acc[nt]);
        }
    }
    // scatter partials: D layout col=lane&15 (out-in-tile), row=quad*4+reg (token)
#pragma unroll
    for (int nt = 0; nt < 12; ++nt)
#pragma unroll
        for (int r = 0; r < 4; ++r)
            Facc[w][quad * 4 + r][nt * 16 + n] = acc[nt][r];
    __syncthreads();

    // merge 4 partials + store.  Q/K: thread t -> token t>>4, cols (t&15)*4.
    {
        const int tok = t >> 4, c0 = (t & 15) * 4;
        float s[4];
        // Q (Wq prescaled by 0.125 -> bias scaled too)
#pragma unroll
        for (int i = 0; i < 4; ++i) s[i] = 0.f;
#pragma unroll
        for (int w4 = 0; w4 < 4; ++w4) {
            const float4 p = *(const float4*)&Facc[w4][tok][c0];
            s[0] += p.x; s[1] += p.y; s[2] += p.z; s[3] += p.w;
        }
        union { ush4 v; unsigned short u[4]; } oq;
#pragma unroll
        for (int i = 0; i < 4; ++i) oq.u[i] = f2bf(s[i] + bq[c0 + i] * 0.125f);
        *(ush4*)(Qg + (size_t)(r0 + tok) * DI + c0) = oq.v;
        // K
#pragma unroll
        for (int i = 0; i < 4; ++i) s[i] = 0.f;
#pragma unroll
        for (int w4 = 0; w4 < 4; ++w4) {
            const float4 p = *(const float4*)&Facc[w4][tok][64 + c0];
            s[0] += p.x; s[1] += p.y; s[2] += p.z; s[3] += p.w;
        }
        union { ush4 v; unsigned short u[4]; } ok;
#pragma unroll
        for (int i = 0; i < 4; ++i) ok.u[i] = f2bf(s[i] + bk[c0 + i]);
        *(ush4*)(Kg + (size_t)(r0 + tok) * DI + c0) = ok.v;
    }
    // V^T: thread t -> dv = t>>2, tokens (t&3)*4 .. +3
    {
        const int dv = t >> 2, t0 = (t & 3) * 4;
        const float bvv = bv[dv];
        union { ush4 v; unsigned short u[4]; } ov;
#pragma unroll
        for (int i = 0; i < 4; ++i) {
            const float vs = Facc[0][t0 + i][128 + dv] + Facc[1][t0 + i][128 + dv]
                           + Facc[2][t0 + i][128 + dv] + Facc[3][t0 + i][128 + dv];
            ov.u[i] = f2bf(vs + bvv);
        }
        const int bidx = r0 >> 11;
        const int tloc = r0 & 2047;
        *(ush4*)(Vtg + (size_t)bidx * DI * SEQ + (size_t)dv * SEQ + tloc + t0) = ov.v;
    }
}

// ---------------------------------------------------------------------------
// Kernel 2: split-K flash attention + fused W0.  grid 1024 = 8 batches x 128
// q-tiles (16 rows), block 256 = 4 waves.  Wave w owns key-chunks kt = w,
// w+4, ... with its OWN online-softmax state and private P buffer -> no
// barrier in the chunk loop.  Then a 2-barrier LSE merge and a per-wave
// 16-col slab of the W0 epilogue.  qt heavy-first, b = idx&7 (XCD affinity).
// ---------------------------------------------------------------------------
__global__ __launch_bounds__(256)
void attn_kernel(const unsigned short* __restrict__ Qg, const unsigned short* __restrict__ Kg,
                 const unsigned short* __restrict__ Vtg, const unsigned short* __restrict__ W0t,
                 const float* __restrict__ b0, float* __restrict__ Out)
{
    __shared__ alignas(16) unsigned short P[4][16][72];   // per-wave P (A-frag layout)
    __shared__ alignas(16) float Ctx[4][16][72];          // per-wave partial ctx
    __shared__ float Mw[4][16], Lw[4][16];
    __shared__ alignas(16) unsigned short Cb[16][72];     // merged ctx, bf16 A-frag layout
    const int t = threadIdx.x;
    const int lane = t & 63, w = t >> 6;
    const int quad = lane >> 4, n = lane & 15;
    const int idx = blockIdx.x;
    const int qt = 127 - (idx >> 3);
    const int b = idx & 7;
    const int q0 = qt * 16;

    const unsigned short* Qb = Qg + ((size_t)b * SEQ + q0) * DI;
    const unsigned short* Kb = Kg + (size_t)b * SEQ * DI;
    const unsigned short* Vb = Vtg + (size_t)b * DI * SEQ;

    const short8 qf0 = *(const short8*)(Qb + n * DI + quad * 8);
    const short8 qf1 = *(const short8*)(Qb + n * DI + 32 + quad * 8);

    const f32x4 ZERO = {0.f, 0.f, 0.f, 0.f};
    float m = -INFINITY, l = 0.f;
    f32x4 ctx[4];
#pragma unroll
    for (int i = 0; i < 4; ++i) ctx[i] = ZERO;

    const int C = (qt >> 2) + 1;                          // causal 64-key chunks
    for (int kt = w; kt < C; kt += 4) {
        const int k0 = kt * 64;
        f32x4 sv[4];
#pragma unroll
        for (int tt = 0; tt < 4; ++tt) {                  // S^T tile: rows = keys
            const unsigned short* kr = Kb + (size_t)(k0 + 16 * tt + n) * DI + quad * 8;
            const short8 kf0 = *(const short8*)kr;
            const short8 kf1 = *(const short8*)(kr + 32);
            f32x4 a = ZERO;
            a = MFMA16(kf0, qf0, a);
            a = MFMA16(kf1, qf1, a);
            sv[tt] = a;                                   // S^T[key=k0+16t+quad*4+r][q=q0+n]
        }
        if (kt == C - 1) {                                // diagonal chunk: causal mask
#pragma unroll
            for (int tt = 0; tt < 4; ++tt)
#pragma unroll
                for (int r = 0; r < 4; ++r)
                    if (k0 + 16 * tt + quad * 4 + r > q0 + n) sv[tt][r] = -INFINITY;
        }
        float rmax = sv[0][0];
#pragma unroll
        for (int tt = 0; tt < 4; ++tt)
#pragma unroll
            for (int r = 0; r < 4; ++r) rmax = fmaxf(rmax, sv[tt][r]);
        rmax = fmaxf(rmax, __shfl_xor(rmax, 16));
        rmax = fmaxf(rmax, __shfl_xor(rmax, 32));
        const float mnew = fmaxf(m, rmax);
        const float alpha = __expf(m - mnew);             // first chunk: exp(-inf)=0
        float rsum = 0.f;
#pragma unroll
        for (int tt = 0; tt < 4; ++tt) {
            union { ush4 v; unsigned short u[4]; } pw;
#pragma unroll
            for (int r = 0; r < 4; ++r) {
                const float p = __expf(sv[tt][r] - mnew);
                rsum += p;
                pw.u[r] = f2bf(p);
            }
            *(ush4*)&P[w][n][16 * tt + quad * 4] = pw.v;  // P[q][key] (wave-private)
        }
        rsum += __shfl_xor(rsum, 16);
        rsum += __shfl_xor(rsum, 32);
        l = l * alpha + rsum;
        m = mnew;
        float aL[4];
#pragma unroll
        for (int r = 0; r < 4; ++r) aL[r] = __shfl(alpha, quad * 4 + r);
#pragma unroll
        for (int nt = 0; nt < 4; ++nt)
#pragma unroll
            for (int r = 0; r < 4; ++r) ctx[nt][r] *= aL[r];
#pragma unroll
        for (int s = 0; s < 2; ++s) {                     // ctx += P V
            const short8 pf = *(const short8*)&P[w][n][s * 32 + quad * 8];
#pragma unroll
            for (int nt = 0; nt < 4; ++nt) {
                const short8 vf = *(const short8*)(Vb + (size_t)(n + 16 * nt) * SEQ + k0 + s * 32 + quad * 8);
                ctx[nt] = MFMA16(pf, vf, ctx[nt]);
            }
        }
    }
    // publish per-wave partials.  ctx[nt][r]: q=quad*4+r, dv=16nt+n.
#pragma unroll
    for (int nt = 0; nt < 4; ++nt)
#pragma unroll
        for (int r = 0; r < 4; ++r)
            Ctx[w][quad * 4 + r][nt * 16 + n] = ctx[nt][r];
    if (quad == 0) { Mw[w][n] = m; Lw[w][n] = l; }        // stats replicated over quads
    __syncthreads();

    // LSE merge: thread t -> q = t>>4, dv = (t&15)*4 .. +3
    {
        const int q = t >> 4, c0 = (t & 15) * 4;
        const float m0 = Mw[0][q], m1 = Mw[1][q], m2 = Mw[2][q], m3 = Mw[3][q];
        const float mstar = fmaxf(fmaxf(m0, m1), fmaxf(m2, m3));
        const float s0 = __expf(m0 - mstar), s1 = __expf(m1 - mstar);
        const float s2 = __expf(m2 - mstar), s3 = __expf(m3 - mstar);
        const float lstar = s0 * Lw[0][q] + s1 * Lw[1][q] + s2 * Lw[2][q] + s3 * Lw[3][q];
        const float4 c0v = *(const float4*)&Ctx[0][q][c0];
        const float4 c1v = *(const float4*)&Ctx[1][q][c0];
        const float4 c2v = *(const float4*)&Ctx[2][q][c0];
        const float4 c3v = *(const float4*)&Ctx[3][q][c0];
        const float inv = 1.0f / lstar;
        union { ush4 v; unsigned short u[4]; } cb;
        cb.u[0] = f2bf((s0 * c0v.x + s1 * c1v.x + s2 * c2v.x + s3 * c3v.x) * inv);
        cb.u[1] = f2bf((s0 * c0v.y + s1 * c1v.y + s2 * c2v.y + s3 * c3v.y) * inv);
        cb.u[2] = f2bf((s0 * c0v.z + s1 * c1v.z + s2 * c2v.z + s3 * c3v.z) * inv);
        cb.u[3] = f2bf((s0 * c0v.w + s1 * c1v.w + s2 * c2v.w + s3 * c3v.w) * inv);
        *(ush4*)&Cb[q][c0] = cb.v;
    }
    __syncthreads();

    // W0 epilogue: wave w computes output columns 16w..16w+15
    f32x4 oacc = ZERO;
#pragma unroll
    for (int s = 0; s < 2; ++s) {
        const short8 cf = *(const short8*)&Cb[n][s * 32 + quad * 8];
        const short8 wf = *(const short8*)(W0t + (size_t)(16 * w + n) * DI + s * 32 + quad * 8);
        oacc = MFMA16(cf, wf, oacc);
    }
    const float bb = b0[16 * w + n];
#pragma unroll
    for (int r = 0; r < 4; ++r)
        Out[((size_t)b * SEQ + q0 + quad * 4 + r) * DI + 16 * w + n] = oacc[r] + bb;
}

// ---------------------------------------------------------------------------
extern "C" void kernel_launch(void* const* d_in, const int* in_sizes, int n_in,
                              void* d_out, int out_size, void* d_ws, size_t ws_size,
                              hipStream_t stream) {
    const float* X  = (const float*)d_in[0];
    const float* Wk = (const float*)d_in[1];
    const float* bk = (const float*)d_in[2];
    const float* Wq = (const float*)d_in[3];
    const float* bq = (const float*)d_in[4];
    const float* Wv = (const float*)d_in[5];
    const float* bv = (const float*)d_in[6];
    const float* W0 = (const float*)d_in[7];
    const float* b0 = (const float*)d_in[8];
    float* Out = (float*)d_out;

    unsigned char* ws = (unsigned char*)d_ws;
    unsigned short* Wt  = (unsigned short*)ws;                        // 192*1024*2 = 384 KiB
    unsigned short* W0t = (unsigned short*)(ws + 393216);             // 64*64*2 = 8 KiB
    unsigned short* Qw  = (unsigned short*)(ws + 401408);             // 2 MiB
    unsigned short* Kw  = (unsigned short*)(ws + 401408 + 2097152);   // 2 MiB
    unsigned short* Vt  = (unsigned short*)(ws + 401408 + 4194304);   // 2 MiB ([8][64][2048])

    convert_kernel<<<49, 256, 0, stream>>>(Wq, Wk, Wv, W0, Wt, W0t);
    proj_kernel<<<1024, 256, 0, stream>>>(X, Wt, bq, bk, bv, Qw, Kw, Vt);
    attn_kernel<<<1024, 256, 0, stream>>>(Qw, Kw, Vt, W0t, b0, Out);
}

// Round 4
// 152.556 us; speedup vs baseline: 3.9114x; 1.2574x over previous
//
#include <hip/hip_runtime.h>
#include <math.h>

#define SEQ 2048
#define DM  1024
#define DI  64

typedef __attribute__((ext_vector_type(8))) short short8;
typedef __attribute__((ext_vector_type(4))) float f32x4;
typedef __attribute__((ext_vector_type(4))) unsigned short ush4;

#define MFMA16(a,b,c) __builtin_amdgcn_mfma_f32_16x16x32_bf16(a,b,c,0,0,0)

// round-to-nearest-even fp32 -> bf16
__device__ __forceinline__ unsigned short f2bf(float f) {
    unsigned int u = __builtin_bit_cast(unsigned int, f);
    u += 0x7fffu + ((u >> 16) & 1u);
    return (unsigned short)(u >> 16);
}

// ---------------------------------------------------------------------------
// Kernel 0: weight prep.  blocks 0..47: Wcat^T bf16 [192][1024] (rows 0-63 =
// Wq^T * 0.125 (exact pow2 fold of 1/sqrt(64)), 64-127 = Wk^T, 128-191 = Wv^T).
// block 48: W0^T bf16 [64][64] + bcat[192] fp32 (bq*0.125 | bk | bv).
// ---------------------------------------------------------------------------
__global__ __launch_bounds__(256)
void convert_kernel(const float* __restrict__ Wq, const float* __restrict__ Wk,
                    const float* __restrict__ Wv, const float* __restrict__ W0,
                    const float* __restrict__ bq, const float* __restrict__ bk,
                    const float* __restrict__ bv,
                    unsigned short* __restrict__ Wt, unsigned short* __restrict__ W0t,
                    float* __restrict__ bcat)
{
    __shared__ float tile[64][65];
    const int t = threadIdx.x;
    const int blk = blockIdx.x;
    const float* src; unsigned short* dst; int k0; float scale; int rstride;
    if (blk < 48) {
        const int mm = blk >> 4, kt = blk & 15;
        src = (mm == 0) ? Wq : (mm == 1) ? Wk : Wv;
        dst = Wt + (size_t)mm * 64 * 1024;
        k0 = kt * 64; scale = (mm == 0) ? 0.125f : 1.0f; rstride = 1024;
    } else {
        src = W0; dst = W0t; k0 = 0; scale = 1.0f; rstride = 64;
        if (t < 192)
            bcat[t] = (t < 64) ? bq[t] * 0.125f : (t < 128) ? bk[t - 64] : bv[t - 128];
    }
#pragma unroll
    for (int i = 0; i < 4; ++i) {
        const int e = i * 1024 + t * 4;
        const int kk = e >> 6, o = e & 63;
        const float4 v = *(const float4*)(src + (size_t)(k0 + kk) * 64 + o);
        tile[kk][o] = v.x; tile[kk][o + 1] = v.y; tile[kk][o + 2] = v.z; tile[kk][o + 3] = v.w;
    }
    __syncthreads();
#pragma unroll
    for (int h = 0; h < 2; ++h) {
        const int o = (t >> 3) + 32 * h;
        const int kp = (t & 7) * 8;
        union { short8 v; unsigned short u[8]; } pk;
#pragma unroll
        for (int j = 0; j < 8; ++j) pk.u[j] = f2bf(tile[kp + j][o] * scale);
        *(short8*)(dst + (size_t)o * rstride + k0 + kp) = pk.v;
    }
}

// ---------------------------------------------------------------------------
// Kernel 1: QKV projection.  512 blocks (32-token tiles) x 4 waves; waves
// split N: wave w owns outs [48w,48w+48) = 3 MFMA tiles -> only 6 B-loads +
// 12 MFMA per BK=64 step, 24 acc VGPRs (room to pipeline B-loads).
// X staged ONCE into a XOR-swizzled bf16 LDS tile (slot = r*8 + (g^(r&7)));
// swizzle keeps the layout linear (no pad) yet bank-conflict-free for both
// the write (lane g distinct per 8-lane phase) and the A-frag b128 reads.
// Full K per wave -> no partial merge; epilogue via LDS transpose.
// ---------------------------------------------------------------------------
__global__ __launch_bounds__(256, 2)
void proj_kernel(const float* __restrict__ X, const unsigned short* __restrict__ Wt,
                 const float* __restrict__ bcat,
                 unsigned short* __restrict__ Qg, unsigned short* __restrict__ Kg,
                 unsigned short* __restrict__ Vtg)
{
    __shared__ alignas(16) unsigned char smem[32 * 200 * 2];   // 12.8 KB, dual-use
    unsigned short* XbS = (unsigned short*)smem;               // 256 slots x 8 bf16

    const int t = threadIdx.x;
    const int lane = t & 63, w = t >> 6;
    const int quad = lane >> 4, n = lane & 15;
    const int r0 = blockIdx.x * 32;

    const f32x4 ZERO = {0.f, 0.f, 0.f, 0.f};
    f32x4 acc[2][3];
#pragma unroll
    for (int a = 0; a < 2; ++a)
#pragma unroll
        for (int j = 0; j < 3; ++j) acc[a][j] = ZERO;

    const int srow = t >> 3, sg = t & 7;
    const int sslot = srow * 8 + (sg ^ (srow & 7));
    const float* xp = X + (size_t)(r0 + srow) * DM + sg * 8;

    const unsigned short* wp0 = Wt + (size_t)((3*w + 0)*16 + n) * DM + quad * 8;
    const unsigned short* wp1 = Wt + (size_t)((3*w + 1)*16 + n) * DM + quad * 8;
    const unsigned short* wp2 = Wt + (size_t)((3*w + 2)*16 + n) * DM + quad * 8;

    for (int ks = 0; ks < 16; ++ks) {
        const int k0 = ks * 64;
        const float4 xa = *(const float4*)(xp + k0);
        const float4 xb = *(const float4*)(xp + k0 + 4);
        short8 bfr[3][2];
#pragma unroll
        for (int s = 0; s < 2; ++s) {
            bfr[0][s] = *(const short8*)(wp0 + k0 + s * 32);
            bfr[1][s] = *(const short8*)(wp1 + k0 + s * 32);
            bfr[2][s] = *(const short8*)(wp2 + k0 + s * 32);
        }
        __syncthreads();                       // prev-iter LDS readers done
        union { short8 v; unsigned short u[8]; } px;
        px.u[0] = f2bf(xa.x); px.u[1] = f2bf(xa.y); px.u[2] = f2bf(xa.z); px.u[3] = f2bf(xa.w);
        px.u[4] = f2bf(xb.x); px.u[5] = f2bf(xb.y); px.u[6] = f2bf(xb.z); px.u[7] = f2bf(xb.w);
        *(short8*)(XbS + sslot * 8) = px.v;
        __syncthreads();                       // staged (barrier drains counts)
        short8 af[2][2];
#pragma unroll
        for (int tt = 0; tt < 2; ++tt)
#pragma unroll
            for (int s = 0; s < 2; ++s) {
                const int slot = (tt*16 + n) * 8 + ((s*4 + quad) ^ (n & 7));
                af[tt][s] = *(const short8*)(XbS + slot * 8);
            }
#pragma unroll
        for (int tt = 0; tt < 2; ++tt)
#pragma unroll
            for (int j = 0; j < 3; ++j) {
                acc[tt][j] = MFMA16(af[tt][0], bfr[j][0], acc[tt][j]);
                acc[tt][j] = MFMA16(af[tt][1], bfr[j][1], acc[tt][j]);
            }
    }

    __syncthreads();
    unsigned short (*Facc)[200] = (unsigned short (*)[200])smem;
    float bias[3];
#pragma unroll
    for (int j = 0; j < 3; ++j) bias[j] = bcat[(3*w + j)*16 + n];
    // D layout: col = lane&15 (out-in-tile), row = quad*4+reg (token-in-16)
#pragma unroll
    for (int tt = 0; tt < 2; ++tt)
#pragma unroll
        for (int j = 0; j < 3; ++j)
#pragma unroll
            for (int r = 0; r < 4; ++r)
                Facc[tt*16 + quad*4 + r][(3*w + j)*16 + n] = f2bf(acc[tt][j][r] + bias[j]);
    __syncthreads();
    // Q/K row-major stores: thread -> token t>>3, 8 cols
    {
        const int tok = t >> 3, c0 = (t & 7) * 8;
        *(short8*)(Qg + (size_t)(r0 + tok) * DI + c0) = *(const short8*)&Facc[tok][c0];
        *(short8*)(Kg + (size_t)(r0 + tok) * DI + c0) = *(const short8*)&Facc[tok][64 + c0];
    }
    // V^T store [b][dv][t]
    {
        const int dv = t & 63, tg = t >> 6;
        union { short8 v; unsigned short u[8]; } ov;
#pragma unroll
        for (int i = 0; i < 8; ++i) ov.u[i] = Facc[tg*8 + i][128 + dv];
        const int bidx = r0 >> 11, tloc = r0 & 2047;
        *(short8*)(Vtg + (size_t)bidx * DI * SEQ + (size_t)dv * SEQ + tloc + tg*8) = ov.v;
    }
}

// ---------------------------------------------------------------------------
// Kernel 2: flash attention + fused W0.  512 blocks = 8 batches x 64 q-tiles
// (32 rows) -> exactly 2 blocks/CU resident.  4 waves split-K (kt = w,w+4,..)
// with wave-private P and softmax state: ZERO barriers in the chunk loop, so
// the compiler can pipeline next-chunk K-loads across iterations.  qt folded
// (heavy+light pairs) for cross-CU balance; b = idx&7 for XCD K/V locality.
// S^T = K.Q^T so stats are per-lane (col=q); P/ctx round-trip wave-private LDS.
// ---------------------------------------------------------------------------
__global__ __launch_bounds__(256, 2)
void attn_kernel(const unsigned short* __restrict__ Qg, const unsigned short* __restrict__ Kg,
                 const unsigned short* __restrict__ Vtg, const unsigned short* __restrict__ W0t,
                 const float* __restrict__ b0, float* __restrict__ Out)
{
    __shared__ alignas(16) unsigned short P[4][32][72];   // wave-private P
    __shared__ alignas(16) float Ctx[4][32][72];          // per-wave partial ctx
    __shared__ float Mw[4][32], Lw[4][32];
    __shared__ alignas(16) unsigned short Cb[32][72];     // merged ctx (A-frag layout)

    const int t = threadIdx.x;
    const int lane = t & 63, w = t >> 6;
    const int quad = lane >> 4, n = lane & 15;
    const int ih = blockIdx.x >> 3;
    const int qt = (ih < 32) ? (63 - ih) : (ih - 32);     // pair heavy+light
    const int b  = blockIdx.x & 7;
    const int q0 = qt * 32;

    const unsigned short* Qb = Qg + ((size_t)b * SEQ + q0) * DI;
    const unsigned short* Kb = Kg + (size_t)b * SEQ * DI;
    const unsigned short* Vb = Vtg + (size_t)b * DI * SEQ;

    short8 qf[2][2];
#pragma unroll
    for (int qh = 0; qh < 2; ++qh)
#pragma unroll
        for (int s = 0; s < 2; ++s)
            qf[qh][s] = *(const short8*)(Qb + (size_t)(qh*16 + n) * DI + s*32 + quad*8);

    const f32x4 ZERO = {0.f, 0.f, 0.f, 0.f};
    float m[2] = {-INFINITY, -INFINITY}, l[2] = {0.f, 0.f};
    f32x4 ctx[2][4];
#pragma unroll
    for (int qh = 0; qh < 2; ++qh)
#pragma unroll
        for (int nt = 0; nt < 4; ++nt) ctx[qh][nt] = ZERO;

    const int C = (qt >> 1) + 1;                          // causal 64-key chunks
    for (int kt = w; kt < C; kt += 4) {
        const int k0 = kt * 64;
        short8 kf[4][2];
#pragma unroll
        for (int tt = 0; tt < 4; ++tt) {
            const unsigned short* kr = Kb + (size_t)(k0 + 16*tt + n) * DI + quad*8;
            kf[tt][0] = *(const short8*)kr;
            kf[tt][1] = *(const short8*)(kr + 32);
        }
        f32x4 sv[2][4];
#pragma unroll
        for (int qh = 0; qh < 2; ++qh)
#pragma unroll
            for (int tt = 0; tt < 4; ++tt) {
                f32x4 a = MFMA16(kf[tt][0], qf[qh][0], ZERO);
                sv[qh][tt] = MFMA16(kf[tt][1], qf[qh][1], a);
            }
        if (kt == C - 1) {                                // diagonal chunk mask
#pragma unroll
            for (int qh = 0; qh < 2; ++qh)
#pragma unroll
                for (int tt = 0; tt < 4; ++tt)
#pragma unroll
                    for (int r = 0; r < 4; ++r)
                        if (k0 + 16*tt + quad*4 + r > q0 + qh*16 + n)
                            sv[qh][tt][r] = -INFINITY;
        }
#pragma unroll
        for (int qh = 0; qh < 2; ++qh) {
            float rmax = sv[qh][0][0];
#pragma unroll
            for (int tt = 0; tt < 4; ++tt)
#pragma unroll
                for (int r = 0; r < 4; ++r) rmax = fmaxf(rmax, sv[qh][tt][r]);
            rmax = fmaxf(rmax, __shfl_xor(rmax, 16));
            rmax = fmaxf(rmax, __shfl_xor(rmax, 32));
            const float mnew = fmaxf(m[qh], rmax);
            const float alpha = __expf(m[qh] - mnew);     // first chunk: exp(-inf)=0
            float rsum = 0.f;
#pragma unroll
            for (int tt = 0; tt < 4; ++tt) {
                union { ush4 v; unsigned short u[4]; } pw;
#pragma unroll
                for (int r = 0; r < 4; ++r) {
                    const float p = __expf(sv[qh][tt][r] - mnew);
                    rsum += p;
                    pw.u[r] = f2bf(p);
                }
                *(ush4*)&P[w][qh*16 + n][16*tt + quad*4] = pw.v;
            }
            rsum += __shfl_xor(rsum, 16);
            rsum += __shfl_xor(rsum, 32);
            l[qh] = l[qh] * alpha + rsum;
            m[qh] = mnew;
            float aL[4];
#pragma unroll
            for (int r = 0; r < 4; ++r) aL[r] = __shfl(alpha, quad*4 + r);
#pragma unroll
            for (int nt = 0; nt < 4; ++nt)
#pragma unroll
                for (int r = 0; r < 4; ++r) ctx[qh][nt][r] *= aL[r];
        }
#pragma unroll
        for (int s = 0; s < 2; ++s) {                     // ctx += P V
            short8 pf[2];
#pragma unroll
            for (int qh = 0; qh < 2; ++qh)
                pf[qh] = *(const short8*)&P[w][qh*16 + n][s*32 + quad*8];
#pragma unroll
            for (int nt = 0; nt < 4; ++nt) {
                const short8 vf = *(const short8*)(Vb + (size_t)(16*nt + n) * SEQ + k0 + s*32 + quad*8);
                ctx[0][nt] = MFMA16(pf[0], vf, ctx[0][nt]);
                ctx[1][nt] = MFMA16(pf[1], vf, ctx[1][nt]);
            }
        }
    }
    // publish per-wave partials (ctx rows: q = qh*16+quad*4+r, cols dv=16nt+n)
#pragma unroll
    for (int qh = 0; qh < 2; ++qh)
#pragma unroll
        for (int nt = 0; nt < 4; ++nt)
#pragma unroll
            for (int r = 0; r < 4; ++r)
                Ctx[w][qh*16 + quad*4 + r][nt*16 + n] = ctx[qh][nt][r];
    if (quad == 0) {
        Mw[w][n] = m[0]; Mw[w][16 + n] = m[1];
        Lw[w][n] = l[0]; Lw[w][16 + n] = l[1];
    }
    __syncthreads();
    // LSE merge: thread t -> q = t>>3, dv cols (t&7)*8 .. +7
    {
        const int q = t >> 3, c0 = (t & 7) * 8;
        const float m0 = Mw[0][q], m1 = Mw[1][q], m2 = Mw[2][q], m3 = Mw[3][q];
        const float ms = fmaxf(fmaxf(m0, m1), fmaxf(m2, m3));
        const float s0 = __expf(m0 - ms), s1 = __expf(m1 - ms);
        const float s2 = __expf(m2 - ms), s3 = __expf(m3 - ms);
        const float inv = 1.0f / (s0*Lw[0][q] + s1*Lw[1][q] + s2*Lw[2][q] + s3*Lw[3][q]);
        union { short8 v; unsigned short u[8]; } cb;
#pragma unroll
        for (int h = 0; h < 2; ++h) {
            const float4 c0v = *(const float4*)&Ctx[0][q][c0 + h*4];
            const float4 c1v = *(const float4*)&Ctx[1][q][c0 + h*4];
            const float4 c2v = *(const float4*)&Ctx[2][q][c0 + h*4];
            const float4 c3v = *(const float4*)&Ctx[3][q][c0 + h*4];
            cb.u[h*4+0] = f2bf((s0*c0v.x + s1*c1v.x + s2*c2v.x + s3*c3v.x) * inv);
            cb.u[h*4+1] = f2bf((s0*c0v.y + s1*c1v.y + s2*c2v.y + s3*c3v.y) * inv);
            cb.u[h*4+2] = f2bf((s0*c0v.z + s1*c1v.z + s2*c2v.z + s3*c3v.z) * inv);
            cb.u[h*4+3] = f2bf((s0*c0v.w + s1*c1v.w + s2*c2v.w + s3*c3v.w) * inv);
        }
        *(short8*)&Cb[q][c0] = cb.v;
    }
    __syncthreads();
    // W0 epilogue: wave w -> out cols 16w..16w+15
    f32x4 oacc[2] = {ZERO, ZERO};
#pragma unroll
    for (int s = 0; s < 2; ++s) {
        const short8 wf = *(const short8*)(W0t + (size_t)(16*w + n) * DI + s*32 + quad*8);
#pragma unroll
        for (int qh = 0; qh < 2; ++qh) {
            const short8 cf = *(const short8*)&Cb[qh*16 + n][s*32 + quad*8];
            oacc[qh] = MFMA16(cf, wf, oacc[qh]);
        }
    }
    const float bb = b0[16*w + n];
#pragma unroll
    for (int qh = 0; qh < 2; ++qh)
#pragma unroll
        for (int r = 0; r < 4; ++r)
            Out[((size_t)b * SEQ + q0 + qh*16 + quad*4 + r) * DI + 16*w + n] = oacc[qh][r] + bb;
}

// ---------------------------------------------------------------------------
extern "C" void kernel_launch(void* const* d_in, const int* in_sizes, int n_in,
                              void* d_out, int out_size, void* d_ws, size_t ws_size,
                              hipStream_t stream) {
    const float* X  = (const float*)d_in[0];
    const float* Wk = (const float*)d_in[1];
    const float* bk = (const float*)d_in[2];
    const float* Wq = (const float*)d_in[3];
    const float* bq = (const float*)d_in[4];
    const float* Wv = (const float*)d_in[5];
    const float* bv = (const float*)d_in[6];
    const float* W0 = (const float*)d_in[7];
    const float* b0 = (const float*)d_in[8];
    float* Out = (float*)d_out;

    unsigned char* ws = (unsigned char*)d_ws;
    unsigned short* Wt   = (unsigned short*)ws;                       // 384 KiB
    unsigned short* W0t  = (unsigned short*)(ws + 393216);            // 8 KiB
    float*          bcat = (float*)(ws + 401408);                     // 768 B
    unsigned short* Qw   = (unsigned short*)(ws + 409600);            // 2 MiB
    unsigned short* Kw   = (unsigned short*)(ws + 409600 + 2097152);  // 2 MiB
    unsigned short* Vt   = (unsigned short*)(ws + 409600 + 4194304);  // 2 MiB

    convert_kernel<<<49, 256, 0, stream>>>(Wq, Wk, Wv, W0, bq, bk, bv, Wt, W0t, bcat);
    proj_kernel<<<512, 256, 0, stream>>>(X, Wt, bcat, Qw, Kw, Vt);
    attn_kernel<<<512, 256, 0, stream>>>(Qw, Kw, Vt, W0t, b0, Out);
}